// Round 4
// baseline (400.305 us; speedup 1.0000x reference)
//
#include <hip/hip_runtime.h>
#include <math.h>

#define B_    1024
#define LK_   1024
#define LQD_  256
#define SQD_  128
#define EPSLN 1e-6f
#define LOG2E 1.4426950408889634f

#define TROWS 16          // rows per tile per wave
#define TF4   33          // float4 slots per padded row (132 floats = 128 + 4 pad)
#define WREGF4 (TROWS * TF4)     // 528 float4 per wave region
#define WREGF  (WREGF4 * 4)      // 2112 floats per wave region

typedef float floatx4 __attribute__((ext_vector_type(4)));  // native vector for nontemporal

__device__ __forceinline__ float gelu_exact(float x) {
    return 0.5f * x * (1.0f + erff(x * 0.70710678118654752f));
}

// One block per batch b (grid=1024), 256 threads = 4 waves, 4 blocks/CU.
// Phase 1: q-path prologue (LN1->W1->GELU->LNq->Wq->u-vectors).
// Phase 2: attention via LDS-tiled two-pass (no per-row shuffle trees).
// Phase 3: epilogue (Wv->Wo->residual->LN2->W2) -> q_out, sc in LDS.
// Phase 4: stream column b of k_out.
__global__ __launch_bounds__(256, 4)
void fused_joint_kernel(
    const float* __restrict__ q_feats, const float* __restrict__ k_feats,
    const int*   __restrict__ msk,
    const float* __restrict__ ln1_g, const float* __restrict__ ln1_b,
    const float* __restrict__ W1,    const float* __restrict__ b1,
    const float* __restrict__ lnq_g, const float* __restrict__ lnq_b,
    const float* __restrict__ lnk_g, const float* __restrict__ lnk_b,
    const float* __restrict__ Wq,    const float* __restrict__ bq,
    const float* __restrict__ Wk,    const float* __restrict__ bk,
    const float* __restrict__ Wv,    const float* __restrict__ bv,
    const float* __restrict__ Wo,    const float* __restrict__ bo,
    const float* __restrict__ scale_w,
    const float* __restrict__ ln2_g, const float* __restrict__ ln2_b,
    const float* __restrict__ W2,    const float* __restrict__ b2,
    float* __restrict__ q_out, float* __restrict__ k_out)
{
    const int b    = blockIdx.x;
    const int tid  = threadIdx.x;
    const int wave = tid >> 6;
    const int lane = tid & 63;

    // ---- LDS layout ----
    __shared__ float4 s_tile4[4 * WREGF4];          // 33792 B, wave-private tiles; aliased for scratch
    __shared__ float4 s_meta[4][TROWS];             // 1024 B : {sc0, sc1, mu, rstd} per row
    __shared__ unsigned short s_idxm[4][256];       // 2048 B : compacted unmasked row indices
    __shared__ __align__(16) float s_gu[2][128];    // 1024 B : g[c]*u_h[c] (SCL folded) -- persistent
    __shared__ float s_q1[128];                     // persistent
    __shared__ float s_sc[128];                     // persistent
    __shared__ float s_red[8];
    __shared__ float s_ml[4][2][2];

    float* s_flat = (float*)s_tile4;
    // prologue aliases (dead once attention staging begins)
    float* s_qn = s_flat;            // 256
    float* s_qi = s_flat + 256;      // 128
    float* s_qh = s_flat + 384;      // 128
    float* s_u0 = s_flat + 512;      // 128 (SCL-folded u, head 0)
    float* s_u1 = s_flat + 640;      // 128
    float* s_c2 = s_flat + 768;      // 2
    // epilogue aliases (alive only after attention loop + syncs)
    float* s_wn  = s_flat + 1024;    // 256  ([2][128])
    float* s_ctx = s_flat + 1280;    // 128
    float* s_qa  = s_flat + 1408;    // 128
    float* s_qn2 = s_flat + 1536;    // 128

    // ---------- prologue: LN1(q_feats[b], 256) ----------
    float x = q_feats[b * LQD_ + tid];
    float rs = x, rss = x * x;
    #pragma unroll
    for (int o = 32; o >= 1; o >>= 1) { rs += __shfl_xor(rs, o); rss += __shfl_xor(rss, o); }
    if (lane == 0) { s_red[wave * 2] = rs; s_red[wave * 2 + 1] = rss; }
    __syncthreads();
    {
        float sum  = s_red[0] + s_red[2] + s_red[4] + s_red[6];
        float ssum = s_red[1] + s_red[3] + s_red[5] + s_red[7];
        float mu   = sum * (1.0f / 256.0f);
        float var  = ssum * (1.0f / 256.0f) - mu * mu;
        float rstd = rsqrtf(var + EPSLN);
        s_qn[tid] = (x - mu) * rstd * ln1_g[tid] + ln1_b[tid];
    }
    __syncthreads();

    // h1 = s_qn @ W1 + b1 ; q1 = gelu(h1)
    if (tid < 128) {
        float acc = b1[tid];
        #pragma unroll 4
        for (int c = 0; c < 256; ++c) acc = fmaf(s_qn[c], W1[c * 128 + tid], acc);
        s_q1[tid] = gelu_exact(acc);
    }
    __syncthreads();

    // LNq(q1) over 128
    float v1 = (tid < 128) ? s_q1[tid] : 0.0f;
    rs = v1; rss = v1 * v1;
    #pragma unroll
    for (int o = 32; o >= 1; o >>= 1) { rs += __shfl_xor(rs, o); rss += __shfl_xor(rss, o); }
    __syncthreads();
    if (lane == 0) { s_red[wave * 2] = rs; s_red[wave * 2 + 1] = rss; }
    __syncthreads();
    {
        float sum  = s_red[0] + s_red[2] + s_red[4] + s_red[6];
        float ssum = s_red[1] + s_red[3] + s_red[5] + s_red[7];
        float mu   = sum * (1.0f / 128.0f);
        float var  = ssum * (1.0f / 128.0f) - mu * mu;
        float rstd = rsqrtf(var + EPSLN);
        if (tid < 128) s_qi[tid] = (v1 - mu) * rstd * lnq_g[tid] + lnq_b[tid];
    }
    __syncthreads();

    // qh = s_qi @ Wq + bq
    if (tid < 128) {
        float acc = bq[tid];
        #pragma unroll 4
        for (int c = 0; c < 128; ++c) acc = fmaf(s_qi[c], Wq[c * 128 + tid], acc);
        s_qh[tid] = acc;
    }
    __syncthreads();

    // u_h[c] = SCL * sum_e Wk[c, h*64+e] * qh[h*64+e]
    const float SCL = 0.125f * LOG2E;
    if (tid < 128) {
        float a0 = 0.f, a1 = 0.f;
        #pragma unroll 4
        for (int e = 0; e < 64; ++e) {
            a0 = fmaf(Wk[tid * 128 + e],      s_qh[e],      a0);
            a1 = fmaf(Wk[tid * 128 + 64 + e], s_qh[64 + e], a1);
        }
        s_u0[tid] = a0 * SCL;
        s_u1[tid] = a1 * SCL;
    }
    if (tid == 0) { float a = 0.f; for (int e = 0; e < 64; ++e) a = fmaf(bk[e],      s_qh[e],      a); s_c2[0] = a * SCL; }
    if (tid == 1) { float a = 0.f; for (int e = 0; e < 64; ++e) a = fmaf(bk[64 + e], s_qh[64 + e], a); s_c2[1] = a * SCL; }
    __syncthreads();

    // build persistent s_gu and per-lane constants; mask compaction
    const int  c0i = lane * 2, c1i = lane * 2 + 1;
    const float g0  = lnk_g[c0i], g1  = lnk_g[c1i];
    const float hb0 = lnk_b[c0i], hb1 = lnk_b[c1i];
    const float u00 = s_u0[c0i], u01 = s_u0[c1i];
    const float u10 = s_u1[c0i], u11 = s_u1[c1i];
    const float cc0 = s_c2[0],   cc1 = s_c2[1];
    if (tid < 128) {
        float g = lnk_g[tid];
        s_gu[0][tid] = s_u0[tid] * g;
        s_gu[1][tid] = s_u1[tid] * g;
    }
    // sgu_h = sum_c g[c]*u_h[c];  d_h = sum_c lnk_b[c]*u_h[c] + cc_h
    float sgu0 = fmaf(g0, u00, g1 * u01);
    float sgu1 = fmaf(g0, u10, g1 * u11);
    float dd0  = fmaf(hb0, u00, hb1 * u01);
    float dd1  = fmaf(hb0, u10, hb1 * u11);
    #pragma unroll
    for (int o = 32; o >= 1; o >>= 1) {
        sgu0 += __shfl_xor(sgu0, o); sgu1 += __shfl_xor(sgu1, o);
        dd0  += __shfl_xor(dd0,  o); dd1  += __shfl_xor(dd1,  o);
    }
    const float d0 = dd0 + cc0, d1 = dd1 + cc1;

    // mask compaction: wave w owns rows [w*256, w*256+256)
    const int* mrow = msk + b * LK_;
    int cnt = 0;
    #pragma unroll
    for (int i = 0; i < 4; ++i) {
        int r = (wave << 8) + (i << 6) + lane;
        int mk = mrow[r];
        unsigned long long bal = __ballot(mk != 0);
        int pre = __popcll(bal & ((1ull << lane) - 1ull));
        if (mk) s_idxm[wave][cnt + pre] = (unsigned short)r;
        cnt += __popcll(bal);
    }
    __syncthreads();   // prologue aliases dead; s_gu/s_idxm visible; tile region free

    // ---------- attention: LDS-tiled two-pass, wave-local ----------
    float4* twave = s_tile4 + wave * WREGF4;
    const float* twf = (const float*)twave;
    const float4* kf4 = (const float4*)k_feats + (size_t)b * (LK_ * 32);
    const float4* gu04 = (const float4*)s_gu[0];
    const float4* gu14 = (const float4*)s_gu[1];
    const int half  = lane >> 5;      // staging: which of 2 rows per load inst
    const int chunk = lane & 31;      // staging: float4 chunk within row
    const int arow  = lane & 15;      // pass A: row within tile
    const int aq    = lane >> 4;      // pass A: quarter of the row

    float m0 = -1e30f, l0 = 0.f, w00 = 0.f, w01 = 0.f;
    float m1 = -1e30f, l1 = 0.f, w10 = 0.f, w11 = 0.f;

    const int ntile = (cnt + TROWS - 1) / TROWS;
    float4 r0v, r1v, r2v, r3v, r4v, r5v, r6v, r7v;
    const float4 z4 = make_float4(0.f, 0.f, 0.f, 0.f);

    #define LOADT(base)                                                        \
    {                                                                          \
        int j_, gi_;                                                           \
        j_ = (base) + 0  + half; gi_ = (j_ < cnt) ? (int)s_idxm[wave][j_] : -1; \
        r0v = (gi_ >= 0) ? kf4[gi_ * 32 + chunk] : z4;                         \
        j_ = (base) + 2  + half; gi_ = (j_ < cnt) ? (int)s_idxm[wave][j_] : -1; \
        r1v = (gi_ >= 0) ? kf4[gi_ * 32 + chunk] : z4;                         \
        j_ = (base) + 4  + half; gi_ = (j_ < cnt) ? (int)s_idxm[wave][j_] : -1; \
        r2v = (gi_ >= 0) ? kf4[gi_ * 32 + chunk] : z4;                         \
        j_ = (base) + 6  + half; gi_ = (j_ < cnt) ? (int)s_idxm[wave][j_] : -1; \
        r3v = (gi_ >= 0) ? kf4[gi_ * 32 + chunk] : z4;                         \
        j_ = (base) + 8  + half; gi_ = (j_ < cnt) ? (int)s_idxm[wave][j_] : -1; \
        r4v = (gi_ >= 0) ? kf4[gi_ * 32 + chunk] : z4;                         \
        j_ = (base) + 10 + half; gi_ = (j_ < cnt) ? (int)s_idxm[wave][j_] : -1; \
        r5v = (gi_ >= 0) ? kf4[gi_ * 32 + chunk] : z4;                         \
        j_ = (base) + 12 + half; gi_ = (j_ < cnt) ? (int)s_idxm[wave][j_] : -1; \
        r6v = (gi_ >= 0) ? kf4[gi_ * 32 + chunk] : z4;                         \
        j_ = (base) + 14 + half; gi_ = (j_ < cnt) ? (int)s_idxm[wave][j_] : -1; \
        r7v = (gi_ >= 0) ? kf4[gi_ * 32 + chunk] : z4;                         \
    }

    if (ntile > 0) LOADT(0);

    for (int t = 0; t < ntile; ++t) {
        // write staged regs into own tile region
        twave[(0  + half) * TF4 + chunk] = r0v;
        twave[(2  + half) * TF4 + chunk] = r1v;
        twave[(4  + half) * TF4 + chunk] = r2v;
        twave[(6  + half) * TF4 + chunk] = r3v;
        twave[(8  + half) * TF4 + chunk] = r4v;
        twave[(10 + half) * TF4 + chunk] = r5v;
        twave[(12 + half) * TF4 + chunk] = r6v;
        twave[(14 + half) * TF4 + chunk] = r7v;
        // prefetch next tile (in flight during pass A/B compute)
        LOADT((t + 1) * TROWS);

        // ---- pass A: 4 lanes per row, 32 elems each ----
        float sx = 0.f, sxx = 0.f, p0 = 0.f, p1 = 0.f;
        const float4* rowp = twave + arow * TF4 + aq * 8;
        #pragma unroll
        for (int k = 0; k < 8; ++k) {
            float4 v  = rowp[k];
            float4 ga = gu04[aq * 8 + k];
            float4 gb = gu14[aq * 8 + k];
            sx += (v.x + v.y) + (v.z + v.w);
            sxx = fmaf(v.x, v.x, fmaf(v.y, v.y, fmaf(v.z, v.z, fmaf(v.w, v.w, sxx))));
            p0  = fmaf(v.x, ga.x, fmaf(v.y, ga.y, fmaf(v.z, ga.z, fmaf(v.w, ga.w, p0))));
            p1  = fmaf(v.x, gb.x, fmaf(v.y, gb.y, fmaf(v.z, gb.z, fmaf(v.w, gb.w, p1))));
        }
        #pragma unroll
        for (int o = 16; o <= 32; o <<= 1) {
            sx += __shfl_xor(sx, o); sxx += __shfl_xor(sxx, o);
            p0 += __shfl_xor(p0, o); p1  += __shfl_xor(p1, o);
        }
        float mu   = sx * (1.f / 128.f);
        float var  = sxx * (1.f / 128.f) - mu * mu;
        float rstd = rsqrtf(var + EPSLN);
        bool  vrow = (t * TROWS + arow) < cnt;
        float sc0  = vrow ? fmaf(rstd, p0 - mu * sgu0, d0) : -1e30f;
        float sc1  = vrow ? fmaf(rstd, p1 - mu * sgu1, d1) : -1e30f;
        if (aq == 0) s_meta[wave][arow] = make_float4(sc0, sc1, mu, rstd);
        // tile max over 16 rows (quarters hold identical values)
        float t0 = sc0, t1 = sc1;
        #pragma unroll
        for (int o = 1; o <= 8; o <<= 1) {
            t0 = fmaxf(t0, __shfl_xor(t0, o));
            t1 = fmaxf(t1, __shfl_xor(t1, o));
        }
        // online rescale to new running max
        float mn0 = fmaxf(m0, t0);
        float cr0 = exp2f(m0 - mn0);
        m0 = mn0; l0 *= cr0; w00 *= cr0; w01 *= cr0;
        float mn1 = fmaxf(m1, t1);
        float cr1 = exp2f(m1 - mn1);
        m1 = mn1; l1 *= cr1; w10 *= cr1; w11 *= cr1;

        // ---- pass B: column-parallel accumulation ----
        #pragma unroll 4
        for (int j = 0; j < TROWS; ++j) {
            float4 mt = s_meta[wave][j];                       // broadcast
            float2 xv = *(const float2*)(twf + j * 132 + 2 * lane);
            float pp0 = exp2f(mt.x - m0);
            float pp1 = exp2f(mt.y - m1);
            float xn0 = (xv.x - mt.z) * mt.w;
            float xn1 = (xv.y - mt.z) * mt.w;
            float kv0 = fmaf(xn0, g0, hb0);
            float kv1 = fmaf(xn1, g1, hb1);
            w00 = fmaf(pp0, kv0, w00); w01 = fmaf(pp0, kv1, w01);
            w10 = fmaf(pp1, kv0, w10); w11 = fmaf(pp1, kv1, w11);
            l0 += pp0; l1 += pp1;
        }
    }
    #undef LOADT

    // ---------- merge 4 waves' partials ----------
    {
        float* myreg = s_flat + wave * WREGF;   // own tile region, now free
        myreg[c0i] = w00; myreg[c1i] = w01;
        myreg[128 + c0i] = w10; myreg[128 + c1i] = w11;
        if (lane == 0) {
            s_ml[wave][0][0] = m0; s_ml[wave][0][1] = l0;
            s_ml[wave][1][0] = m1; s_ml[wave][1][1] = l1;
        }
    }
    __syncthreads();

    if (tid < 128) {
        #pragma unroll
        for (int h = 0; h < 2; ++h) {
            float mg = fmaxf(fmaxf(s_ml[0][h][0], s_ml[1][h][0]),
                             fmaxf(s_ml[2][h][0], s_ml[3][h][0]));
            float lt = 0.f, wt = 0.f;
            #pragma unroll
            for (int wv = 0; wv < 4; ++wv) {
                float e = exp2f(s_ml[wv][h][0] - mg);
                lt += s_ml[wv][h][1] * e;
                wt += s_flat[wv * WREGF + h * 128 + tid] * e;
            }
            s_wn[h * 128 + tid] = wt / lt;
        }
    }
    __syncthreads();

    // ctx = (w/l) @ Wv + bv
    if (tid < 128) {
        int h = tid >> 6;
        float acc = bv[tid];
        #pragma unroll 4
        for (int c = 0; c < 128; ++c) acc = fmaf(s_wn[h * 128 + c], Wv[c * 128 + tid], acc);
        s_ctx[tid] = acc;
    }
    __syncthreads();

    // attn_out = gelu(ctx @ Wo + bo); q_atten_final = q1 + attn_out
    if (tid < 128) {
        float acc = bo[tid];
        #pragma unroll 4
        for (int c = 0; c < 128; ++c) acc = fmaf(s_ctx[c], Wo[c * 128 + tid], acc);
        float qa = s_q1[tid] + gelu_exact(acc);
        s_qa[tid] = qa;
        s_sc[tid] = qa * scale_w[tid];
    }
    __syncthreads();

    // LN2(q_atten_final) over 128
    float v2 = (tid < 128) ? s_qa[tid] : 0.0f;
    rs = v2; rss = v2 * v2;
    #pragma unroll
    for (int o = 32; o >= 1; o >>= 1) { rs += __shfl_xor(rs, o); rss += __shfl_xor(rss, o); }
    __syncthreads();
    if (lane == 0) { s_red[wave * 2] = rs; s_red[wave * 2 + 1] = rss; }
    __syncthreads();
    {
        float sum  = s_red[0] + s_red[2] + s_red[4] + s_red[6];
        float ssum = s_red[1] + s_red[3] + s_red[5] + s_red[7];
        float mu   = sum * (1.0f / 128.0f);
        float var  = ssum * (1.0f / 128.0f) - mu * mu;
        float rstd = rsqrtf(var + EPSLN);
        if (tid < 128) s_qn2[tid] = (v2 - mu) * rstd * ln2_g[tid] + ln2_b[tid];
    }
    __syncthreads();

    // q_out = q_feats + gelu(qn2 @ W2 + b2)
    {
        float acc = b2[tid];
        #pragma unroll 4
        for (int c = 0; c < 128; ++c) acc = fmaf(s_qn2[c], W2[c * 256 + tid], acc);
        q_out[b * LQD_ + tid] = q_feats[b * LQD_ + tid] + gelu_exact(acc);
    }

    // ---------- stream column b of k_out ----------
    // k_out[b2, b, :] = k_feats[b2, b, :] + sc[b, :]
    {
        const int c4 = tid & 31;
        const int rr = tid >> 5;
        const float4 sv = ((const float4*)s_sc)[c4];
        const size_t colbase = (size_t)b * 32 + c4;
        const floatx4* __restrict__ kin4  = (const floatx4*)k_feats;
        floatx4*       __restrict__ kout4 = (floatx4*)k_out;
        #pragma unroll 4
        for (int b2 = rr; b2 < B_; b2 += 8) {
            size_t o = (size_t)b2 * (LK_ * 32) + colbase;
            floatx4 kx = kin4[o];
            floatx4 ov;
            ov.x = kx.x + sv.x; ov.y = kx.y + sv.y;
            ov.z = kx.z + sv.z; ov.w = kx.w + sv.w;
            __builtin_nontemporal_store(ov, &kout4[o]);
        }
    }
}

extern "C" void kernel_launch(void* const* d_in, const int* in_sizes, int n_in,
                              void* d_out, int out_size, void* d_ws, size_t ws_size,
                              hipStream_t stream)
{
    (void)in_sizes; (void)n_in; (void)out_size; (void)d_ws; (void)ws_size;
    const float* q_feats = (const float*)d_in[0];
    const float* k_feats = (const float*)d_in[1];
    const int*   msk     = (const int*)d_in[2];
    const float* ln1_g   = (const float*)d_in[3];
    const float* ln1_b   = (const float*)d_in[4];
    const float* W1      = (const float*)d_in[5];
    const float* b1      = (const float*)d_in[6];
    const float* lnq_g   = (const float*)d_in[7];
    const float* lnq_b   = (const float*)d_in[8];
    const float* lnk_g   = (const float*)d_in[9];
    const float* lnk_b   = (const float*)d_in[10];
    const float* Wq      = (const float*)d_in[11];
    const float* bq      = (const float*)d_in[12];
    const float* Wk      = (const float*)d_in[13];
    const float* bk      = (const float*)d_in[14];
    const float* Wv      = (const float*)d_in[15];
    const float* bv      = (const float*)d_in[16];
    const float* Wo      = (const float*)d_in[17];
    const float* bo      = (const float*)d_in[18];
    const float* scale_w = (const float*)d_in[19];
    const float* ln2_g   = (const float*)d_in[20];
    const float* ln2_b   = (const float*)d_in[21];
    const float* W2      = (const float*)d_in[22];
    const float* b2      = (const float*)d_in[23];

    float* q_out = (float*)d_out;                           // 1024*256
    float* k_out = (float*)d_out + (size_t)B_ * LQD_;       // 1024*1024*128

    fused_joint_kernel<<<B_, 256, 0, stream>>>(
        q_feats, k_feats, msk, ln1_g, ln1_b, W1, b1, lnq_g, lnq_b,
        lnk_g, lnk_b, Wq, bq, Wk, bk, Wv, bv, Wo, bo, scale_w,
        ln2_g, ln2_b, W2, b2, q_out, k_out);
}